// Round 10
// baseline (259.732 us; speedup 1.0000x reference)
//
#include <hip/hip_runtime.h>
#include <math.h>

// B=2, S=2048, D=1024, H=16, DK=64, rope_dim=32, causal MHA. fp32 in/out.
// convert->bf16 (+Lp zero) | QKV MFMA-GEMM dbuf (+fast RoPE, scatter) | memset Op |
// barrier-free per-wave MFMA flash (direct L2->register K/V, S^T orientation,
// register P-transpose, fp32 atomic partials) | normalize | out GEMM.

static constexpr int Bb  = 2;
static constexpr int Ss  = 2048;
static constexpr int Hh  = 16;
static constexpr int DKk = 64;

static constexpr size_t QSZ = (size_t)Bb * Hh * Ss * DKk;   // 4,194,304

// ws bytes: Wo[0,2M) | x[2M,10M) | Wqkv[10M,16M) | Q[18M,26M) | K[26M,34M) |
//           Vt[34M,42M) | Ob[42M,50M) | Lp[50M,50.25M). Op fp32 overlays [2M,18M).
static constexpr size_t WOB_E  = 0;
static constexpr size_t XB_E   = 1048576;
static constexpr size_t WQKV_E = 5242880;
static constexpr size_t QB_E   = 9437184;
static constexpr size_t OB_E   = QB_E + 3*QSZ;
static constexpr size_t OP_BYTE = 2097152;
static constexpr size_t LP_BYTE = 52428800;

typedef __attribute__((ext_vector_type(8))) short short8;
typedef __attribute__((ext_vector_type(4))) float f32x4;

__device__ __forceinline__ unsigned short f2bf(float f) {   // RNE
    unsigned int u = __float_as_uint(f);
    u += 0x7fffu + ((u >> 16) & 1u);
    return (unsigned short)(u >> 16);
}

// round-half-up packed bf16x2: 4 VALU ops. P>=0, finite.
__device__ __forceinline__ unsigned int pk_hu(float lo, float hi) {
    const unsigned int ul = __float_as_uint(lo) + 0x8000u;
    const unsigned int uh = __float_as_uint(hi) + 0x8000u;
    return (uh & 0xffff0000u) | (ul >> 16);
}

__device__ __forceinline__ float fexp2(float x) {           // 2^x, exp2(-inf)=0
    float r;
    asm("v_exp_f32 %0, %1" : "=v"(r) : "v"(x));
    return r;
}

__device__ __forceinline__ float fsin_rev(float r) {        // sin(2*pi*r)
    float o;
    asm("v_sin_f32 %0, %1" : "=v"(o) : "v"(r));
    return o;
}
__device__ __forceinline__ float fcos_rev(float r) {
    float o;
    asm("v_cos_f32 %0, %1" : "=v"(o) : "v"(r));
    return o;
}

__device__ __forceinline__ void gl16(const unsigned short* g, unsigned short* l) {
    __builtin_amdgcn_global_load_lds(
        (const __attribute__((address_space(1))) void*)g,
        (__attribute__((address_space(3))) void*)l, 16, 0, 0);
}

// ---------------------------------------------------------------------------
// fp32->bf16 of Wo | x | Wqkv into ws; blocks >= 8192 zero Lp (64 blocks).
// ---------------------------------------------------------------------------
__global__ __launch_bounds__(256)
void convert_bf16(const float* __restrict__ x, const float* __restrict__ wqkv,
                  const float* __restrict__ wo, unsigned short* __restrict__ dst,
                  float* __restrict__ Lp)
{
    if (blockIdx.x >= 8192) {
        const size_t j4 = ((size_t)(blockIdx.x - 8192) * 256 + threadIdx.x) * 4;
        *(float4*)(Lp + j4) = float4{0.f, 0.f, 0.f, 0.f};
        return;
    }
    const size_t i4 = ((size_t)blockIdx.x * 256 + threadIdx.x) * 4;
    const float* src;
    if (i4 < 1048576)      src = wo   + i4;
    else if (i4 < 5242880) src = x    + (i4 - 1048576);
    else                   src = wqkv + (i4 - 5242880);
    const float4 v = *(const float4*)src;
    ushort4 p = { f2bf(v.x), f2bf(v.y), f2bf(v.z), f2bf(v.w) };
    *(ushort4*)(dst + i4) = p;
}

// ---------------------------------------------------------------------------
// bf16 MFMA GEMM, dbuf with distinct LDS arrays. C = A[M,K] * B[N,K]^T,
// K=1024, BK=32, BM=128, BN=128|64.  MODE 0: C fp32.  MODE 1: QKV scatter
// + fused RoPE (HW v_sin/v_cos, revolutions); Q pre-scaled by log2(e)/8.
// ---------------------------------------------------------------------------
template<int MODE, int BN>
__global__ __launch_bounds__(256)
void gemm_mfma(const unsigned short* __restrict__ A,
               const unsigned short* __restrict__ Bm,
               float* __restrict__ C, unsigned short* __restrict__ QKV, int N)
{
    constexpr int K  = 1024;
    constexpr int NF = BN / 32;
    __shared__ unsigned short As0[128 * 32];
    __shared__ unsigned short As1[128 * 32];
    __shared__ unsigned short Bs0[BN * 32];
    __shared__ unsigned short Bs1[BN * 32];

    const int t    = threadIdx.x;
    const int lane = t & 63;
    const int w    = t >> 6;
    const int l15  = lane & 15;
    const int quad = lane >> 4;
    const int wr   = w >> 1;
    const int wc   = w & 1;
    const int n0   = blockIdx.x * BN;
    const int m0   = blockIdx.y * 128;

    const unsigned short* Ag = A  + (size_t)(m0 + (t >> 2)) * K + (t & 3) * 8;
    const unsigned short* Bg = Bm + (size_t)(n0 + (t >> 2)) * K + (t & 3) * 8;

    f32x4 acc[4][NF];
    #pragma unroll
    for (int i = 0; i < 4; i++)
        #pragma unroll
        for (int j = 0; j < NF; j++) acc[i][j] = f32x4{0.f, 0.f, 0.f, 0.f};

    auto stage = [&](int k0, unsigned short* Asb, unsigned short* Bsb) {
        gl16(Ag + k0,        Asb + t*8);
        gl16(Ag + 64*K + k0, Asb + 2048 + t*8);
        gl16(Bg + k0,        Bsb + t*8);
        if (BN == 128) gl16(Bg + 64*K + k0, Bsb + 2048 + t*8);
    };
    auto comp = [&](const unsigned short* Asb, const unsigned short* Bsb) {
        short8 af[4], bfv[NF];
        #pragma unroll
        for (int mf = 0; mf < 4; mf++)
            af[mf] = *(const short8*)&Asb[(wr*64 + mf*16 + l15) * 32 + quad*8];
        #pragma unroll
        for (int nf = 0; nf < NF; nf++)
            bfv[nf] = *(const short8*)&Bsb[(wc*(BN/2) + nf*16 + l15) * 32 + quad*8];
        #pragma unroll
        for (int mf = 0; mf < 4; mf++)
            #pragma unroll
            for (int nf = 0; nf < NF; nf++)
                acc[mf][nf] = __builtin_amdgcn_mfma_f32_16x16x32_bf16(
                    af[mf], bfv[nf], acc[mf][nf], 0, 0, 0);
    };

    stage(0, As0, Bs0);
    for (int k0 = 0; k0 < K; k0 += 64) {
        __syncthreads();
        stage(k0 + 32, As1, Bs1);
        comp(As0, Bs0);
        __syncthreads();
        if (k0 + 64 < K) stage(k0 + 64, As0, Bs0);
        comp(As1, Bs1);
    }

    if (MODE == 0) {
        #pragma unroll
        for (int mf = 0; mf < 4; mf++)
            #pragma unroll
            for (int r = 0; r < 4; r++) {
                float* crow = C + (size_t)(m0 + wr*64 + mf*16 + quad*4 + r) * N
                            + n0 + wc*(BN/2);
                #pragma unroll
                for (int nf = 0; nf < NF; nf++)
                    crow[nf*16 + l15] = acc[mf][nf][r];
            }
    } else {
        const int col0 = n0 + wc*64;           // wave-uniform (BN=128)
        const int q    = col0 >> 10;
        const int h    = (col0 >> 6) & 15;
        const int row0 = m0 + wr*64;
        const int b    = row0 >> 11;
        const int s0   = row0 & 2047;
        if (q == 2) {
            #pragma unroll
            for (int mf = 0; mf < 4; mf++) {
                const int sb = s0 + mf*16 + quad*4;
                #pragma unroll
                for (int nf = 0; nf < 4; nf++) {
                    const int d = nf*16 + l15;
                    ushort4 p = { f2bf(acc[mf][nf][0]), f2bf(acc[mf][nf][1]),
                                  f2bf(acc[mf][nf][2]), f2bf(acc[mf][nf][3]) };
                    *(ushort4*)(QKV + 2*QSZ
                        + ((size_t)((b*Hh + h) * DKk + d)) * Ss + sb) = p;
                }
            }
        } else {
            // Q scale folds 1/sqrt(64) and log2(e) for flash's exp2 softmax
            const float qsc = (q == 0) ? 0.125f * 1.44269504088896f : 1.0f;
            const float rev_freq = (float)(exp(-(double)(2 * l15) / 32.0
                                   * log(6000.0)) / 6.283185307179586);
            unsigned short* base = QKV + (size_t)q * QSZ
                                 + ((size_t)(b*Hh + h) * Ss) * DKk;
            #pragma unroll
            for (int mf = 0; mf < 4; mf++)
                #pragma unroll
                for (int r = 0; r < 4; r++) {
                    const int s = s0 + mf*16 + quad*4 + r;
                    float rev = (float)s * rev_freq;
                    rev -= floorf(rev);
                    const float sn = fsin_rev(rev);
                    const float cs = fcos_rev(rev);
                    const float v0 = acc[mf][0][r] * qsc;
                    const float v1 = acc[mf][1][r] * qsc;
                    unsigned short* rowp = base + (size_t)s * DKk;
                    rowp[l15]      = f2bf(v0 * cs - v1 * sn);
                    rowp[16 + l15] = f2bf(v1 * cs + v0 * sn);
                    rowp[32 + l15] = f2bf(acc[mf][2][r] * qsc);
                    rowp[48 + l15] = f2bf(acc[mf][3][r] * qsc);
                }
        }
    }
}

// ---------------------------------------------------------------------------
// Barrier-free per-WAVE MFMA causal flash. Wave item = (bh, qt32, kt):
// q-tile 32 rows (qt32 of 64), k-tile 64 keys, kt in [0, qt32/2]. 1056
// items/bh, 33792 total. XCD x = bid&7 owns bh [4x,4x+4) (K+V 2 MB -> per-XCD
// L2); 512 wave-slots/XCD take 8-9 contiguous items. NO LDS, NO barriers:
// K A-frags (8 x b128) and V B-frags (16 x b64) load straight from L2 into
// registers. S^T orientation (A=K, B=Q) -> P stays in-lane; PV uses permuted
// reduction index sigma(kc,quad,j)=32kc+16(j>>2)+4quad+(j&3) so the P A-frag
// is a register pack and V frags are contiguous b64s. Max-free exp2 softmax
// -> additive partials -> fp32 atomicAdd into Op/Lp.
// ---------------------------------------------------------------------------
__global__ __launch_bounds__(256)
void flash_mfma(const unsigned short* __restrict__ Qa,
                const unsigned short* __restrict__ Ka,
                const unsigned short* __restrict__ Va,
                float* __restrict__ Op, float* __restrict__ Lp)
{
    const int t    = threadIdx.x;
    const int lane = t & 63;
    const int w    = t >> 6;
    const int l15  = lane & 15;
    const int quad = lane >> 4;

    // schedule: 4224 items per XCD over 512 wave-slots
    const int bid  = blockIdx.x;
    const int xcd  = bid & 7;
    const int slot = (bid >> 3) * 4 + w;
    const int start = (slot < 128) ? 9*slot : 1152 + 8*(slot - 128);
    const int n     = (slot < 128) ? 9 : 8;

    // decode within-XCD item index -> (bh, qt32, kt)
    int bh  = xcd*4 + start / 1056;
    int rem = start % 1056;
    // cum(2m)=m*m+m, cum(2m+1)=(m+1)^2
    int s = (int)sqrtf((float)rem);
    while ((s+1)*(s+1) <= rem) s++;
    while (s*s > rem) s--;
    int qt, kt;
    if (rem < s*s + s) { qt = 2*s - 1; kt = rem - s*s; }
    else               { qt = 2*s;     kt = rem - s*s - s; }

    short8 qf[2][2];          // [mfq][kc]  B-frags of Q
    f32x4 o[2][4];            // [mfq][dt]  O C-frags
    float lacc[2];
    auto zero_acc = [&]() {
        #pragma unroll
        for (int mfq = 0; mfq < 2; mfq++) {
            lacc[mfq] = 0.f;
            #pragma unroll
            for (int i = 0; i < 4; i++) o[mfq][i] = f32x4{0.f,0.f,0.f,0.f};
        }
    };
    auto loadQ = [&](int qbh, int qqt) {
        #pragma unroll
        for (int mfq = 0; mfq < 2; mfq++) {
            const unsigned short* qrow = Qa + (size_t)qbh * Ss * DKk
                + (size_t)(qqt*32 + mfq*16 + l15) * DKk;
            qf[mfq][0] = *(const short8*)(qrow + quad*8);
            qf[mfq][1] = *(const short8*)(qrow + 32 + quad*8);
        }
    };
    auto flush = [&](int obh, int oqt) {
        const int b = obh >> 4, h = obh & 15;
        const int q0 = oqt*32;
        #pragma unroll
        for (int mfq = 0; mfq < 2; mfq++) {
            float ls = lacc[mfq];
            ls += __shfl_xor(ls, 16);
            ls += __shfl_xor(ls, 32);
            if (quad == 0)
                atomicAdd(&Lp[(size_t)obh*Ss + q0 + mfq*16 + l15], ls);
            #pragma unroll
            for (int r = 0; r < 4; r++) {
                const int row = q0 + mfq*16 + quad*4 + r;
                float* orow = Op + ((size_t)b*Ss + row) * 1024 + h*64;
                #pragma unroll
                for (int dt = 0; dt < 4; dt++)
                    atomicAdd(&orow[dt*16 + l15], o[mfq][dt][r]);
            }
        }
    };
    auto compute = [&](int cbh, int cqt, int ckt) {
        const unsigned short* Kt = Ka + ((size_t)cbh * Ss + ckt*64) * DKk;
        const unsigned short* Vt = Va + (size_t)cbh * DKk * Ss + ckt*64;

        // issue all K + V loads together (L2-resident; latency overlapped)
        short8 kf[4][2];
        #pragma unroll
        for (int nt = 0; nt < 4; nt++) {
            const unsigned short* kr = Kt + (size_t)(nt*16 + l15) * DKk + quad*8;
            kf[nt][0] = *(const short8*)(kr);
            kf[nt][1] = *(const short8*)(kr + 32);
        }
        ushort4 vlo[4][2], vhi[4][2];
        #pragma unroll
        for (int dt = 0; dt < 4; dt++) {
            const unsigned short* vr = Vt + (size_t)(dt*16 + l15) * Ss + 4*quad;
            #pragma unroll
            for (int kc = 0; kc < 2; kc++) {
                vlo[dt][kc] = *(const ushort4*)(vr + 32*kc);
                vhi[dt][kc] = *(const ushort4*)(vr + 32*kc + 16);
            }
        }

        // S^T = K Q^T : D[m=key nt*16+4quad+r][n=q mfq*16+l15]
        f32x4 sc[4][2];
        #pragma unroll
        for (int nt = 0; nt < 4; nt++)
            #pragma unroll
            for (int mfq = 0; mfq < 2; mfq++) sc[nt][mfq] = f32x4{0.f,0.f,0.f,0.f};
        #pragma unroll
        for (int nt = 0; nt < 4; nt++)
            #pragma unroll
            for (int kc = 0; kc < 2; kc++) {
                sc[nt][0] = __builtin_amdgcn_mfma_f32_16x16x32_bf16(kf[nt][kc], qf[0][kc], sc[nt][0], 0,0,0);
                sc[nt][1] = __builtin_amdgcn_mfma_f32_16x16x32_bf16(kf[nt][kc], qf[1][kc], sc[nt][1], 0,0,0);
            }

        if (ckt == (cqt >> 1)) {                // diagonal tile
            const int kb = ckt*64 + quad*4;
            const int qb = cqt*32 + l15;
            #pragma unroll
            for (int nt = 0; nt < 4; nt++)
                #pragma unroll
                for (int mfq = 0; mfq < 2; mfq++)
                    #pragma unroll
                    for (int r = 0; r < 4; r++)
                        if (kb + nt*16 + r > qb + mfq*16)
                            sc[nt][mfq][r] = -INFINITY;
        }

        #pragma unroll
        for (int nt = 0; nt < 4; nt++)
            #pragma unroll
            for (int mfq = 0; mfq < 2; mfq++)
                #pragma unroll
                for (int r = 0; r < 4; r++)
                    sc[nt][mfq][r] = fexp2(sc[nt][mfq][r]);
        #pragma unroll
        for (int mfq = 0; mfq < 2; mfq++)
            #pragma unroll
            for (int nt = 0; nt < 4; nt++)
                lacc[mfq] += (sc[nt][mfq][0] + sc[nt][mfq][1])
                           + (sc[nt][mfq][2] + sc[nt][mfq][3]);

        // P A-frags via sigma (register pack, round-half-up)
        short8 pfrag[2][2];                    // [mfq][kc]
        #pragma unroll
        for (int mfq = 0; mfq < 2; mfq++)
            #pragma unroll
            for (int kc = 0; kc < 2; kc++) {
                unsigned int pk[4];
                #pragma unroll
                for (int v = 0; v < 4; v++) {
                    const int nt = 2*kc + (v >> 1);
                    const int rr = 2*(v & 1);
                    pk[v] = pk_hu(sc[nt][mfq][rr], sc[nt][mfq][rr+1]);
                }
                pfrag[mfq][kc] = *(short8*)&pk[0];
            }

        // O += P V : vf(dt,kc) = keys 32kc+4quad+{0..3} (lo), +16 (hi) at d row
        #pragma unroll
        for (int dt = 0; dt < 4; dt++)
            #pragma unroll
            for (int kc = 0; kc < 2; kc++) {
                short8 vf;
                vf[0]=vlo[dt][kc].x; vf[1]=vlo[dt][kc].y;
                vf[2]=vlo[dt][kc].z; vf[3]=vlo[dt][kc].w;
                vf[4]=vhi[dt][kc].x; vf[5]=vhi[dt][kc].y;
                vf[6]=vhi[dt][kc].z; vf[7]=vhi[dt][kc].w;
                o[0][dt] = __builtin_amdgcn_mfma_f32_16x16x32_bf16(
                    pfrag[0][kc], vf, o[0][dt], 0,0,0);
                o[1][dt] = __builtin_amdgcn_mfma_f32_16x16x32_bf16(
                    pfrag[1][kc], vf, o[1][dt], 0,0,0);
            }
    };

    int own_bh = bh, own_qt = qt;
    loadQ(own_bh, own_qt);
    zero_acc();
    for (int i = 0; i < n; i++) {
        if (bh != own_bh || qt != own_qt) {
            flush(own_bh, own_qt); zero_acc();
            own_bh = bh; own_qt = qt; loadQ(own_bh, own_qt);
        }
        compute(bh, qt, kt);
        kt++;
        if (kt > (qt >> 1)) { kt = 0; qt++; if (qt == 64) { qt = 0; bh++; } }
    }
    flush(own_bh, own_qt);
}

// ---------------------------------------------------------------------------
__global__ __launch_bounds__(256)
void reduce_o(const float* __restrict__ Op, const float* __restrict__ Lp,
              unsigned short* __restrict__ Ob)
{
    const size_t i4 = ((size_t)blockIdx.x * 256 + threadIdx.x) * 4;
    const int row = (int)(i4 >> 10);          // b*2048 + s
    const int col = (int)(i4 & 1023);
    const int h   = col >> 6;
    const int b   = row >> 11;
    const int s   = row & 2047;
    const float inv = 1.0f / Lp[(size_t)((b << 4) + h) * Ss + s];
    const float4 v = *(const float4*)(Op + i4);
    ushort4 p = { f2bf(v.x*inv), f2bf(v.y*inv), f2bf(v.z*inv), f2bf(v.w*inv) };
    *(ushort4*)(Ob + i4) = p;
}

// ---------------------------------------------------------------------------
extern "C" void kernel_launch(void* const* d_in, const int* in_sizes, int n_in,
                              void* d_out, int out_size, void* d_ws, size_t ws_size,
                              hipStream_t stream)
{
    const float* x    = (const float*)d_in[0];
    const float* Wqkv = (const float*)d_in[1];
    const float* Wo   = (const float*)d_in[2];
    float* out = (float*)d_out;
    unsigned short* wsu = (unsigned short*)d_ws;
    float* Op = (float*)((char*)d_ws + OP_BYTE);
    float* Lp = (float*)((char*)d_ws + LP_BYTE);

    const dim3 blk(256);
    convert_bf16<<<dim3(8256), blk, 0, stream>>>(x, Wqkv, Wo, wsu, Lp);
    gemm_mfma<1,128><<<dim3(24, 32), blk, 0, stream>>>(wsu + XB_E, wsu + WQKV_E,
                                                       nullptr, wsu + QB_E, 3072);
    hipMemsetAsync((char*)d_ws + OP_BYTE, 0, 16777216, stream);
    flash_mfma<<<dim3(1024), blk, 0, stream>>>(wsu + QB_E, wsu + QB_E + QSZ,
                                               wsu + QB_E + 2*QSZ, Op, Lp);
    reduce_o<<<dim3(4096), blk, 0, stream>>>(Op, Lp, wsu + OB_E);
    gemm_mfma<0,64><<<dim3(16, 32), blk, 0, stream>>>(wsu + OB_E, wsu + WOB_E,
                                                      out, nullptr, 1024);
}

// Round 11
// 209.050 us; speedup vs baseline: 1.2424x; 1.2424x over previous
//
#include <hip/hip_runtime.h>
#include <math.h>

// B=2, S=2048, D=1024, H=16, DK=64, rope_dim=32, causal MHA. fp32 in/out.
// convert->bf16 (+Lp zero) | QKV MFMA-GEMM dbuf (+fast RoPE, scatter) | memset Op |
// XCD-clustered balanced MFMA flash (round-8 structure: LDS dbuf staging,
// S^T orientation, in-register P-transpose, fp32 atomic partials) |
// normalize | out GEMM.

static constexpr int Bb  = 2;
static constexpr int Ss  = 2048;
static constexpr int Hh  = 16;
static constexpr int DKk = 64;

static constexpr size_t QSZ = (size_t)Bb * Hh * Ss * DKk;   // 4,194,304

// ws bytes: Wo[0,2M) | x[2M,10M) | Wqkv[10M,16M) | Q[18M,26M) | K[26M,34M) |
//           Vt[34M,42M) | Ob[42M,50M) | Lp[50M,50.25M). Op fp32 overlays [2M,18M).
static constexpr size_t WOB_E  = 0;
static constexpr size_t XB_E   = 1048576;
static constexpr size_t WQKV_E = 5242880;
static constexpr size_t QB_E   = 9437184;
static constexpr size_t OB_E   = QB_E + 3*QSZ;
static constexpr size_t OP_BYTE = 2097152;
static constexpr size_t LP_BYTE = 52428800;

typedef __attribute__((ext_vector_type(8))) short short8;
typedef __attribute__((ext_vector_type(4))) float f32x4;

__device__ __forceinline__ unsigned short f2bf(float f) {   // RNE
    unsigned int u = __float_as_uint(f);
    u += 0x7fffu + ((u >> 16) & 1u);
    return (unsigned short)(u >> 16);
}

// round-half-up packed bf16x2: 4 VALU ops (vs 9 for RNE pair). P>=0, finite.
__device__ __forceinline__ unsigned int pk_hu(float lo, float hi) {
    const unsigned int ul = __float_as_uint(lo) + 0x8000u;
    const unsigned int uh = __float_as_uint(hi) + 0x8000u;
    return (uh & 0xffff0000u) | (ul >> 16);
}

__device__ __forceinline__ float fexp2(float x) {           // 2^x, exp2(-inf)=0
    float r;
    asm("v_exp_f32 %0, %1" : "=v"(r) : "v"(x));
    return r;
}

__device__ __forceinline__ float fsin_rev(float r) {        // sin(2*pi*r)
    float o;
    asm("v_sin_f32 %0, %1" : "=v"(o) : "v"(r));
    return o;
}
__device__ __forceinline__ float fcos_rev(float r) {
    float o;
    asm("v_cos_f32 %0, %1" : "=v"(o) : "v"(r));
    return o;
}

__device__ __forceinline__ void gl16(const unsigned short* g, unsigned short* l) {
    __builtin_amdgcn_global_load_lds(
        (const __attribute__((address_space(1))) void*)g,
        (__attribute__((address_space(3))) void*)l, 16, 0, 0);
}

// ---------------------------------------------------------------------------
// fp32->bf16 of Wo | x | Wqkv into ws; blocks >= 8192 zero Lp (64 blocks).
// ---------------------------------------------------------------------------
__global__ __launch_bounds__(256)
void convert_bf16(const float* __restrict__ x, const float* __restrict__ wqkv,
                  const float* __restrict__ wo, unsigned short* __restrict__ dst,
                  float* __restrict__ Lp)
{
    if (blockIdx.x >= 8192) {
        const size_t j4 = ((size_t)(blockIdx.x - 8192) * 256 + threadIdx.x) * 4;
        *(float4*)(Lp + j4) = float4{0.f, 0.f, 0.f, 0.f};
        return;
    }
    const size_t i4 = ((size_t)blockIdx.x * 256 + threadIdx.x) * 4;
    const float* src;
    if (i4 < 1048576)      src = wo   + i4;
    else if (i4 < 5242880) src = x    + (i4 - 1048576);
    else                   src = wqkv + (i4 - 5242880);
    const float4 v = *(const float4*)src;
    ushort4 p = { f2bf(v.x), f2bf(v.y), f2bf(v.z), f2bf(v.w) };
    *(ushort4*)(dst + i4) = p;
}

// ---------------------------------------------------------------------------
// bf16 MFMA GEMM, dbuf with distinct LDS arrays. C = A[M,K] * B[N,K]^T,
// K=1024, BK=32, BM=128, BN=128|64.  MODE 0: C fp32.  MODE 1: QKV scatter
// + fused RoPE (HW v_sin/v_cos, revolutions); Q pre-scaled by log2(e)/8.
// ---------------------------------------------------------------------------
template<int MODE, int BN>
__global__ __launch_bounds__(256)
void gemm_mfma(const unsigned short* __restrict__ A,
               const unsigned short* __restrict__ Bm,
               float* __restrict__ C, unsigned short* __restrict__ QKV, int N)
{
    constexpr int K  = 1024;
    constexpr int NF = BN / 32;
    __shared__ unsigned short As0[128 * 32];
    __shared__ unsigned short As1[128 * 32];
    __shared__ unsigned short Bs0[BN * 32];
    __shared__ unsigned short Bs1[BN * 32];

    const int t    = threadIdx.x;
    const int lane = t & 63;
    const int w    = t >> 6;
    const int l15  = lane & 15;
    const int quad = lane >> 4;
    const int wr   = w >> 1;
    const int wc   = w & 1;
    const int n0   = blockIdx.x * BN;
    const int m0   = blockIdx.y * 128;

    const unsigned short* Ag = A  + (size_t)(m0 + (t >> 2)) * K + (t & 3) * 8;
    const unsigned short* Bg = Bm + (size_t)(n0 + (t >> 2)) * K + (t & 3) * 8;

    f32x4 acc[4][NF];
    #pragma unroll
    for (int i = 0; i < 4; i++)
        #pragma unroll
        for (int j = 0; j < NF; j++) acc[i][j] = f32x4{0.f, 0.f, 0.f, 0.f};

    auto stage = [&](int k0, unsigned short* Asb, unsigned short* Bsb) {
        gl16(Ag + k0,        Asb + t*8);
        gl16(Ag + 64*K + k0, Asb + 2048 + t*8);
        gl16(Bg + k0,        Bsb + t*8);
        if (BN == 128) gl16(Bg + 64*K + k0, Bsb + 2048 + t*8);
    };
    auto comp = [&](const unsigned short* Asb, const unsigned short* Bsb) {
        short8 af[4], bfv[NF];
        #pragma unroll
        for (int mf = 0; mf < 4; mf++)
            af[mf] = *(const short8*)&Asb[(wr*64 + mf*16 + l15) * 32 + quad*8];
        #pragma unroll
        for (int nf = 0; nf < NF; nf++)
            bfv[nf] = *(const short8*)&Bsb[(wc*(BN/2) + nf*16 + l15) * 32 + quad*8];
        #pragma unroll
        for (int mf = 0; mf < 4; mf++)
            #pragma unroll
            for (int nf = 0; nf < NF; nf++)
                acc[mf][nf] = __builtin_amdgcn_mfma_f32_16x16x32_bf16(
                    af[mf], bfv[nf], acc[mf][nf], 0, 0, 0);
    };

    stage(0, As0, Bs0);
    for (int k0 = 0; k0 < K; k0 += 64) {
        __syncthreads();
        stage(k0 + 32, As1, Bs1);
        comp(As0, Bs0);
        __syncthreads();
        if (k0 + 64 < K) stage(k0 + 64, As0, Bs0);
        comp(As1, Bs1);
    }

    if (MODE == 0) {
        #pragma unroll
        for (int mf = 0; mf < 4; mf++)
            #pragma unroll
            for (int r = 0; r < 4; r++) {
                float* crow = C + (size_t)(m0 + wr*64 + mf*16 + quad*4 + r) * N
                            + n0 + wc*(BN/2);
                #pragma unroll
                for (int nf = 0; nf < NF; nf++)
                    crow[nf*16 + l15] = acc[mf][nf][r];
            }
    } else {
        const int col0 = n0 + wc*64;           // wave-uniform (BN=128)
        const int q    = col0 >> 10;
        const int h    = (col0 >> 6) & 15;
        const int row0 = m0 + wr*64;
        const int b    = row0 >> 11;
        const int s0   = row0 & 2047;
        if (q == 2) {
            #pragma unroll
            for (int mf = 0; mf < 4; mf++) {
                const int sb = s0 + mf*16 + quad*4;
                #pragma unroll
                for (int nf = 0; nf < 4; nf++) {
                    const int d = nf*16 + l15;
                    ushort4 p = { f2bf(acc[mf][nf][0]), f2bf(acc[mf][nf][1]),
                                  f2bf(acc[mf][nf][2]), f2bf(acc[mf][nf][3]) };
                    *(ushort4*)(QKV + 2*QSZ
                        + ((size_t)((b*Hh + h) * DKk + d)) * Ss + sb) = p;
                }
            }
        } else {
            // Q scale folds 1/sqrt(64) and log2(e) for flash's exp2 softmax
            const float qsc = (q == 0) ? 0.125f * 1.44269504088896f : 1.0f;
            const float rev_freq = (float)(exp(-(double)(2 * l15) / 32.0
                                   * log(6000.0)) / 6.283185307179586);
            unsigned short* base = QKV + (size_t)q * QSZ
                                 + ((size_t)(b*Hh + h) * Ss) * DKk;
            #pragma unroll
            for (int mf = 0; mf < 4; mf++)
                #pragma unroll
                for (int r = 0; r < 4; r++) {
                    const int s = s0 + mf*16 + quad*4 + r;
                    float rev = (float)s * rev_freq;
                    rev -= floorf(rev);
                    const float sn = fsin_rev(rev);
                    const float cs = fcos_rev(rev);
                    const float v0 = acc[mf][0][r] * qsc;
                    const float v1 = acc[mf][1][r] * qsc;
                    unsigned short* rowp = base + (size_t)s * DKk;
                    rowp[l15]      = f2bf(v0 * cs - v1 * sn);
                    rowp[16 + l15] = f2bf(v1 * cs + v0 * sn);
                    rowp[32 + l15] = f2bf(acc[mf][2][r] * qsc);
                    rowp[48 + l15] = f2bf(acc[mf][3][r] * qsc);
                }
        }
    }
}

// ---------------------------------------------------------------------------
// XCD-clustered balanced MFMA causal flash (round-8 structure). Work item =
// (bh, QT, kt): q-tile 128 rows, k-tile 64 keys, kt in [0, 2QT+2); 272 items
// per bh. XCD x = bid&7 owns bh [4x,4x+4); 128 slots/XCD take 8-9 items;
// grid 1024 = exact co-residency (4 blocks/CU), no tail.
// S computed TRANSPOSED (A=K, B=Q) -> P stays in-lane; PV uses permuted
// reduction index sigma(kc,quad,j)=32kc+16(j>>2)+4quad+(j&3): the P A-frag
// is a half-up register pack; V B-frag = two ds_read_b64 with same sigma.
// Max-free exp2 softmax -> additive partials -> fp32 atomicAdd into Op/Lp.
// ---------------------------------------------------------------------------
__global__ __launch_bounds__(256)
void flash_mfma(const unsigned short* __restrict__ Qa,
                const unsigned short* __restrict__ Ka,
                const unsigned short* __restrict__ Va,
                float* __restrict__ Op, float* __restrict__ Lp)
{
    __shared__ unsigned short Ks0[64*64];
    __shared__ unsigned short Ks1[64*64];
    __shared__ unsigned short Vs0[64*64];
    __shared__ unsigned short Vs1[64*64];

    const int t    = threadIdx.x;
    const int lane = t & 63;
    const int w    = t >> 6;
    const int l15  = lane & 15;
    const int quad = lane >> 4;

    // XCD-clustered balanced split: 1088 items/XCD over 128 slots
    const int bid   = blockIdx.x;
    const int xcd   = bid & 7;
    const int slot  = bid >> 3;
    const int start = xcd*1088 + (slot < 64 ? 9*slot : 576 + 8*(slot - 64));
    const int n     = (slot < 64) ? 9 : 8;

    int bh  = start / 272;
    int rem = start - bh*272;
    int QT  = 0;
    while ((QT+1)*(QT+2) <= rem) QT++;
    int kt  = rem - QT*(QT+1);

    const int c0 = t,       r0 = c0 >> 3, g0 = ((c0 & 7) ^ (r0 & 7)) * 8;
    const int c1 = t + 256, r1 = c1 >> 3, g1 = ((c1 & 7) ^ (r1 & 7)) * 8;

    auto stage = [&](int sbh, int skt, unsigned short* Ksb, unsigned short* Vsb) {
        const unsigned short* Kg = Ka + (size_t)sbh * Ss * DKk + (size_t)skt*64*DKk;
        const unsigned short* Vg = Va + (size_t)sbh * DKk * Ss + skt*64;
        gl16(Kg + (size_t)r0*DKk + g0, Ksb + t*8);
        gl16(Kg + (size_t)r1*DKk + g1, Ksb + (t+256)*8);
        gl16(Vg + (size_t)r0*Ss  + g0, Vsb + t*8);
        gl16(Vg + (size_t)r1*Ss  + g1, Vsb + (t+256)*8);
    };

    short8 qf[2][2];          // [mfq][kc]  B-frags of Q
    f32x4 o[2][4];            // [mfq][dt]  O C-frags
    float lacc[2];            // row-sum partial (this quad's keys)
    auto zero_acc = [&]() {
        #pragma unroll
        for (int mfq = 0; mfq < 2; mfq++) {
            lacc[mfq] = 0.f;
            #pragma unroll
            for (int i = 0; i < 4; i++) o[mfq][i] = f32x4{0.f,0.f,0.f,0.f};
        }
    };
    auto loadQ = [&](int qbh, int qQT) {
        #pragma unroll
        for (int mfq = 0; mfq < 2; mfq++) {
            const unsigned short* qrow = Qa + (size_t)qbh * Ss * DKk
                + (size_t)(qQT*128 + w*32 + mfq*16 + l15) * DKk;
            qf[mfq][0] = *(const short8*)(qrow + quad*8);
            qf[mfq][1] = *(const short8*)(qrow + 32 + quad*8);
        }
    };
    auto flush = [&](int obh, int oQT) {
        const int b = obh >> 4, h = obh & 15;
        const int q0 = oQT*128 + w*32;
        #pragma unroll
        for (int mfq = 0; mfq < 2; mfq++) {
            float ls = lacc[mfq];
            ls += __shfl_xor(ls, 16);      // sum the 4 quads' key partials
            ls += __shfl_xor(ls, 32);
            if (quad == 0)
                atomicAdd(&Lp[(size_t)obh*Ss + q0 + mfq*16 + l15], ls);
            #pragma unroll
            for (int r = 0; r < 4; r++) {
                const int row = q0 + mfq*16 + quad*4 + r;
                float* orow = Op + ((size_t)b*Ss + row) * 1024 + h*64;
                #pragma unroll
                for (int dt = 0; dt < 4; dt++)
                    atomicAdd(&orow[dt*16 + l15], o[mfq][dt][r]);
            }
        }
    };
    auto compute = [&](const unsigned short* Ksb, const unsigned short* Vsb,
                       int cQT, int ckt) {
        // S^T = K Q^T : D[m=key nt*16+4quad+r][n=q w*32+mfq*16+l15]
        f32x4 sc[4][2];
        #pragma unroll
        for (int nt = 0; nt < 4; nt++)
            #pragma unroll
            for (int mfq = 0; mfq < 2; mfq++) sc[nt][mfq] = f32x4{0.f,0.f,0.f,0.f};
        #pragma unroll
        for (int nt = 0; nt < 4; nt++)
            #pragma unroll
            for (int kc = 0; kc < 2; kc++) {
                const short8 kf = *(const short8*)&Ksb[(nt*16 + l15)*64
                                   + (((kc*4 + quad) ^ (l15 & 7)) * 8)];
                sc[nt][0] = __builtin_amdgcn_mfma_f32_16x16x32_bf16(kf, qf[0][kc], sc[nt][0], 0,0,0);
                sc[nt][1] = __builtin_amdgcn_mfma_f32_16x16x32_bf16(kf, qf[1][kc], sc[nt][1], 0,0,0);
            }

        if (ckt >= 2*cQT) {                     // diagonal tiles only
            const int kb = ckt*64 + quad*4;
            const int qb = cQT*128 + w*32 + l15;
            #pragma unroll
            for (int nt = 0; nt < 4; nt++)
                #pragma unroll
                for (int mfq = 0; mfq < 2; mfq++)
                    #pragma unroll
                    for (int r = 0; r < 4; r++)
                        if (kb + nt*16 + r > qb + mfq*16)
                            sc[nt][mfq][r] = -INFINITY;
        }

        #pragma unroll
        for (int nt = 0; nt < 4; nt++)
            #pragma unroll
            for (int mfq = 0; mfq < 2; mfq++)
                #pragma unroll
                for (int r = 0; r < 4; r++)
                    sc[nt][mfq][r] = fexp2(sc[nt][mfq][r]);
        #pragma unroll
        for (int mfq = 0; mfq < 2; mfq++)
            #pragma unroll
            for (int nt = 0; nt < 4; nt++)
                lacc[mfq] += (sc[nt][mfq][0] + sc[nt][mfq][1])
                           + (sc[nt][mfq][2] + sc[nt][mfq][3]);

        // P A-frags via sigma: frag (mfq,kc) word v packs
        // sc[2kc+(v>>1)][mfq][2(v&1)] (lo), sc[2kc+(v>>1)][mfq][2(v&1)+1] (hi)
        short8 pfrag[2][2];                    // [mfq][kc]
        #pragma unroll
        for (int mfq = 0; mfq < 2; mfq++)
            #pragma unroll
            for (int kc = 0; kc < 2; kc++) {
                unsigned int pk[4];
                #pragma unroll
                for (int v = 0; v < 4; v++) {
                    const int nt = 2*kc + (v >> 1);
                    const int rr = 2*(v & 1);
                    pk[v] = pk_hu(sc[nt][mfq][rr], sc[nt][mfq][rr+1]);
                }
                pfrag[mfq][kc] = *(short8*)&pk[0];
            }

        // O += P V with sigma-permuted V B-frags (two b64 reads each)
        #pragma unroll
        for (int dt = 0; dt < 4; dt++) {
            const int row = dt*16 + l15;       // d row of Vt tile
            const int rx  = row & 7;
            const int wi  = 4*(quad & 1);
            #pragma unroll
            for (int kc = 0; kc < 2; kc++) {
                const ushort4 lo = *(const ushort4*)&Vsb[row*64
                                    + (((4*kc + (quad>>1)) ^ rx) * 8) + wi];
                const ushort4 hi = *(const ushort4*)&Vsb[row*64
                                    + (((4*kc + 2 + (quad>>1)) ^ rx) * 8) + wi];
                short8 vf;
                vf[0]=lo.x; vf[1]=lo.y; vf[2]=lo.z; vf[3]=lo.w;
                vf[4]=hi.x; vf[5]=hi.y; vf[6]=hi.z; vf[7]=hi.w;
                o[0][dt] = __builtin_amdgcn_mfma_f32_16x16x32_bf16(
                    pfrag[0][kc], vf, o[0][dt], 0,0,0);
                o[1][dt] = __builtin_amdgcn_mfma_f32_16x16x32_bf16(
                    pfrag[1][kc], vf, o[1][dt], 0,0,0);
            }
        }
    };

    int cbh = bh, cQT = QT, ckt = kt;           // current
    int pbh = bh, pQT = QT, pkt = kt;           // prefetch cursor
    auto advance = [&]() {
        pkt++;
        if (pkt == 2*pQT + 2) { pkt = 0; pQT++; if (pQT == 16) { pQT = 0; pbh++; } }
    };

    stage(pbh, pkt, Ks0, Vs0);
    advance();
    int own_bh = cbh, own_QT = cQT;
    loadQ(own_bh, own_QT);
    zero_acc();

    int i = 0;
    while (true) {
        __syncthreads();
        const bool h1 = (i + 1 < n);
        if (h1) stage(pbh, pkt, Ks1, Vs1);
        if (cbh != own_bh || cQT != own_QT) {
            flush(own_bh, own_QT); zero_acc();
            own_bh = cbh; own_QT = cQT; loadQ(own_bh, own_QT);
        }
        compute(Ks0, Vs0, cQT, ckt);
        if (!h1) break;
        cbh = pbh; cQT = pQT; ckt = pkt; advance();
        i++;
        __syncthreads();
        const bool h2 = (i + 1 < n);
        if (h2) stage(pbh, pkt, Ks0, Vs0);
        if (cbh != own_bh || cQT != own_QT) {
            flush(own_bh, own_QT); zero_acc();
            own_bh = cbh; own_QT = cQT; loadQ(own_bh, own_QT);
        }
        compute(Ks1, Vs1, cQT, ckt);
        if (!h2) break;
        cbh = pbh; cQT = pQT; ckt = pkt; advance();
        i++;
    }
    flush(own_bh, own_QT);
}

// ---------------------------------------------------------------------------
__global__ __launch_bounds__(256)
void reduce_o(const float* __restrict__ Op, const float* __restrict__ Lp,
              unsigned short* __restrict__ Ob)
{
    const size_t i4 = ((size_t)blockIdx.x * 256 + threadIdx.x) * 4;
    const int row = (int)(i4 >> 10);          // b*2048 + s
    const int col = (int)(i4 & 1023);
    const int h   = col >> 6;
    const int b   = row >> 11;
    const int s   = row & 2047;
    const float inv = 1.0f / Lp[(size_t)((b << 4) + h) * Ss + s];
    const float4 v = *(const float4*)(Op + i4);
    ushort4 p = { f2bf(v.x*inv), f2bf(v.y*inv), f2bf(v.z*inv), f2bf(v.w*inv) };
    *(ushort4*)(Ob + i4) = p;
}

// ---------------------------------------------------------------------------
extern "C" void kernel_launch(void* const* d_in, const int* in_sizes, int n_in,
                              void* d_out, int out_size, void* d_ws, size_t ws_size,
                              hipStream_t stream)
{
    const float* x    = (const float*)d_in[0];
    const float* Wqkv = (const float*)d_in[1];
    const float* Wo   = (const float*)d_in[2];
    float* out = (float*)d_out;
    unsigned short* wsu = (unsigned short*)d_ws;
    float* Op = (float*)((char*)d_ws + OP_BYTE);
    float* Lp = (float*)((char*)d_ws + LP_BYTE);

    const dim3 blk(256);
    convert_bf16<<<dim3(8256), blk, 0, stream>>>(x, Wqkv, Wo, wsu, Lp);
    gemm_mfma<1,128><<<dim3(24, 32), blk, 0, stream>>>(wsu + XB_E, wsu + WQKV_E,
                                                       nullptr, wsu + QB_E, 3072);
    hipMemsetAsync((char*)d_ws + OP_BYTE, 0, 16777216, stream);
    flash_mfma<<<dim3(1024), blk, 0, stream>>>(wsu + QB_E, wsu + QB_E + QSZ,
                                               wsu + QB_E + 2*QSZ, Op, Lp);
    reduce_o<<<dim3(4096), blk, 0, stream>>>(Op, Lp, wsu + OB_E);
    gemm_mfma<0,64><<<dim3(16, 32), blk, 0, stream>>>(wsu + OB_E, wsu + WOB_E,
                                                      out, nullptr, 1024);
}